// Round 1
// 1350.386 us; speedup vs baseline: 1.0612x; 1.0612x over previous
//
#include <hip/hip_runtime.h>

#ifndef __has_builtin
#define __has_builtin(x) 0
#endif

// ---- fast HW transcendentals (v_exp_f32 computes 2^x; v_rcp_f32) ----
__device__ __forceinline__ float fast_exp2(float x) {
#if __has_builtin(__builtin_amdgcn_exp2f)
  return __builtin_amdgcn_exp2f(x);
#else
  return exp2f(x);
#endif
}
__device__ __forceinline__ float fast_rcp(float x) {
#if __has_builtin(__builtin_amdgcn_rcpf)
  return __builtin_amdgcn_rcpf(x);
#else
  return 1.0f / x;
#endif
}

namespace {
constexpr int kB = 131072;
constexpr int kSeq = 150;
constexpr int kD = 2;
constexpr int kH = 64;
constexpr int kPred = 150;
constexpr int kSteps = kPred - 1;            // 149
constexpr float kDt = 150.0f / 149.0f;       // linspace(0,150,150) spacing
constexpr float kC = 2.8853900817779268f;    // 2*log2(e)
constexpr int kSplit = 4;                    // lanes per batch element
constexpr int kHper = kH / kSplit;           // 16 hidden units per lane
constexpr int kBlock = 256;
constexpr int kElemsPerBlock = kBlock / kSplit;  // 64
}  // namespace

// Butterfly add within each 4-lane quad via DPP quad_perm (pure VALU, no LDS).
// xor1: perm(1,0,3,2) = 0xB1 ; xor2: perm(2,3,0,1) = 0x4E
__device__ __forceinline__ float dpp_xor1_add(float v) {
  int s = __builtin_amdgcn_update_dpp(0, __float_as_int(v), 0xB1, 0xF, 0xF, true);
  return v + __int_as_float(s);
}
__device__ __forceinline__ float dpp_xor2_add(float v) {
  int s = __builtin_amdgcn_update_dpp(0, __float_as_int(v), 0x4E, 0xF, 0xF, true);
  return v + __int_as_float(s);
}

// f(y) = tanh(y@W1+b1)@W2 + b2, folded:
//   tanh(q) = 1 - 2*rcp(1 + exp2(q*2log2e))
//   per-lane (16 of 64 hidden units): wx=W1[0][j]*C, wy=W1[1][j]*C,
//   wb=b1[j]*C, wz=-2*W2[j][0], ww=-2*W2[j][1]
//   lane partial base: 0.25*b2[d] + sum_own_j W2[j][d]; quad butterfly sums
//   partials -> every lane of the quad holds identical f (a+b == b+a in fp).
__global__ __launch_bounds__(kBlock, 4) void ode_kernel(
    const float* __restrict__ x, const float* __restrict__ W1,
    const float* __restrict__ b1, const float* __restrict__ W2,
    const float* __restrict__ b2, float* __restrict__ out) {
  const int t = threadIdx.x;
  const int part = t & (kSplit - 1);
  const int j0 = part * kHper;

  // Weights live entirely in VGPRs: all indices below are compile-time
  // constants after full unroll (rule: runtime-indexed arrays -> scratch).
  float wx[kHper], wy[kHper], wz[kHper], ww[kHper], wb[kHper];
#pragma unroll
  for (int i = 0; i < kHper; ++i) {
    const int j = j0 + i;
    // W1 is (D,H) row-major; W2 is (H,D) row-major.
    wx[i] = W1[j] * kC;
    wy[i] = W1[kH + j] * kC;
    wb[i] = b1[j] * kC;
    wz[i] = -2.0f * W2[2 * j];
    ww[i] = -2.0f * W2[2 * j + 1];
  }
  float pb0 = 0.25f * b2[0];
  float pb1 = 0.25f * b2[1];
#pragma unroll
  for (int i = 0; i < kHper; ++i) {
    // partial sum of W2[j][d] over own j (wz = -2*W2 -> multiply by -0.5)
    pb0 = fmaf(-0.5f, wz[i], pb0);
    pb1 = fmaf(-0.5f, ww[i], pb1);
  }

  const long elem = (long)blockIdx.x * kElemsPerBlock + (t >> 2);
  const float* xp = x + elem * (long)(kSeq * kD) + (kSeq - 1) * kD;
  float y0 = xp[0];
  float y1 = xp[1];
  float* op = out + elem * (long)(kPred * kD);

  auto feval = [&](float u0, float u1, float& f0, float& f1) {
    float a0 = pb0, a1 = pb1, c0 = 0.0f, c1 = 0.0f;  // dual accumulators (ILP)
#pragma unroll
    for (int i = 0; i < kHper; i += 2) {
      float p0 = fmaf(u0, wx[i], fmaf(u1, wy[i], wb[i]));
      float r0 = fast_rcp(1.0f + fast_exp2(p0));
      a0 = fmaf(r0, wz[i], a0);
      a1 = fmaf(r0, ww[i], a1);
      float p1 = fmaf(u0, wx[i + 1], fmaf(u1, wy[i + 1], wb[i + 1]));
      float r1 = fast_rcp(1.0f + fast_exp2(p1));
      c0 = fmaf(r1, wz[i + 1], c0);
      c1 = fmaf(r1, ww[i + 1], c1);
    }
    a0 += c0;
    a1 += c1;
    // 4-lane butterfly: every lane ends with the full 64-hidden sum.
    a0 = dpp_xor2_add(dpp_xor1_add(a0));
    a1 = dpp_xor2_add(dpp_xor1_add(a1));
    f0 = a0;
    f1 = a1;
  };

  // previous even-index state (for paired float4 stores)
  float py0 = y0, py1 = y1;
  constexpr float DT = kDt, DT3 = kDt / 3.0f, DT8 = kDt / 8.0f;

  for (int s = 1; s <= kSteps; ++s) {
    float k1x, k1y, k2x, k2y, k3x, k3y, k4x, k4y;
    feval(y0, y1, k1x, k1y);
    feval(fmaf(DT3, k1x, y0), fmaf(DT3, k1y, y1), k2x, k2y);
    feval(fmaf(DT, k2x, fmaf(-DT3, k1x, y0)),
          fmaf(DT, k2y, fmaf(-DT3, k1y, y1)), k3x, k3y);
    feval(fmaf(DT, k1x - k2x + k3x, y0),
          fmaf(DT, k1y - k2y + k3y, y1), k4x, k4y);
    y0 = fmaf(DT8, k1x + 3.0f * (k2x + k3x) + k4x, y0);
    y1 = fmaf(DT8, k1y + 3.0f * (k2y + k3y) + k4y, y1);

    if (s & 1) {
      if (part == 0) {
        // write times (s-1, s) as one 16B store; offsets are 16B-aligned
        float4 v = make_float4(py0, py1, y0, y1);
        *reinterpret_cast<float4*>(op + (long)(s - 1) * 2) = v;
      }
    } else {
      py0 = y0;
      py1 = y1;
    }
  }
}

extern "C" void kernel_launch(void* const* d_in, const int* in_sizes, int n_in,
                              void* d_out, int out_size, void* d_ws,
                              size_t ws_size, hipStream_t stream) {
  const float* x = (const float*)d_in[0];
  const float* W1 = (const float*)d_in[1];
  const float* b1 = (const float*)d_in[2];
  const float* W2 = (const float*)d_in[3];
  const float* b2 = (const float*)d_in[4];
  float* out = (float*)d_out;

  dim3 grid(kB * kSplit / kBlock);  // 2048 blocks, 4 lanes per element
  dim3 block(kBlock);
  hipLaunchKernelGGL(ode_kernel, grid, block, 0, stream, x, W1, b1, W2, b2,
                     out);
}